// Round 7
// baseline (281.935 us; speedup 1.0000x reference)
//
#include <hip/hip_runtime.h>

#define TT 256
#define BB 8192
#define DD 16
#define HH 8

#define INV_2PI 0.15915494309189535f

__device__ __forceinline__ float fast_rcp(float v) { return __builtin_amdgcn_rcpf(v); }

// quad broadcast via DPP: every lane of the quad reads lane (quadbase + g)
#define QBCAST(x, g) __int_as_float(__builtin_amdgcn_mov_dpp(__float_as_int(x), (g)*0x55, 0xF, 0xF, true))

// cross-lane gather: result = src-value of lane (addr/4)
__device__ __forceinline__ float bperm(int addr, float v) {
    return __int_as_float(__builtin_amdgcn_ds_bpermute(addr, __float_as_int(v)));
}

__global__ __launch_bounds__(256, 2)
void qlstm_fused_kernel(const float* __restrict__ inp,
                        const float* __restrict__ Wf, const float* __restrict__ bfv,
                        const float* __restrict__ Wi, const float* __restrict__ biv,
                        const float* __restrict__ Wu, const float* __restrict__ buv,
                        const float* __restrict__ Wo, const float* __restrict__ bov,
                        const float* __restrict__ pf, const float* __restrict__ pi,
                        const float* __restrict__ pu, const float* __restrict__ po,
                        float* __restrict__ out)
{
    const int tid  = blockIdx.x * blockDim.x + threadIdx.x;
    const int gate = tid & 3;          // 0=f, 1=i, 2=u(g), 3=o  (quad lanes)
    const int part = (tid >> 2) & 3;   // owns matvec rows / wires 2*part, 2*part+1
    const int b    = tid >> 4;         // sample

    const float* Wg = (gate == 0) ? Wf  : (gate == 1) ? Wi  : (gate == 2) ? Wu  : Wo;
    const float* bg = (gate == 0) ? bfv : (gate == 1) ? biv : (gate == 2) ? buv : bov;
    const float* pp = (gate == 0) ? pf  : (gate == 1) ? pi  : (gate == 2) ? pu  : po;

    // ---- own 2 weight rows (48 floats) + biases in VGPRs ----
    const int r0 = 2 * part;
    float w0[24], w1[24];
    {
        const float* p0 = Wg + r0 * 24;
        const float* p1 = Wg + (r0 + 1) * 24;
        #pragma unroll
        for (int k = 0; k < 6; ++k) {
            float4 v0 = *(const float4*)(p0 + 4 * k);
            float4 v1 = *(const float4*)(p1 + 4 * k);
            w0[4*k+0] = v0.x; w0[4*k+1] = v0.y; w0[4*k+2] = v0.z; w0[4*k+3] = v0.w;
            w1[4*k+0] = v1.x; w1[4*k+1] = v1.y; w1[4*k+2] = v1.z; w1[4*k+3] = v1.w;
        }
    }
    const float bs0 = bg[r0], bs1 = bg[r0 + 1];

    // ---- layer-1 trig: OWN wires only; layer-2 trig: full arrays (recursion coeffs) ----
    float s1o0, c1o0, s1o1, c1o1;
    __sincosf(pp[r0],     &s1o0, &c1o0);
    __sincosf(pp[r0 + 1], &s1o1, &c1o1);
    float g2[HH], hn[HH];
    #pragma unroll
    for (int w = 0; w < HH; ++w) {
        float s, c;
        __sincosf(pp[HH + w], &s, &c);
        g2[w] = c; hn[w] = -s;
    }

    // gate nonlinearity constants: sigmoid for f/i/o; tanh(v) = 2*sig(2v)-1 for u
    const float kPre  = (gate == 2) ? -2.0f : -1.0f;
    const float kPost = (gate == 2) ?  2.0f :  1.0f;
    const float kAdd  = (gate == 2) ? -1.0f :  0.0f;

    const bool pl = (part & 1) != 0;   // position within xor4 pair
    const bool hi = (part & 2) != 0;   // which 4-wire group we own

    // ---- bpermute gather addresses (byte): target lane = samplegroup | (k<<2) | gate ----
    const int lane = threadIdx.x & 63;
    const int sg   = lane & ~15;
    const int A0 = (sg | 0  | gate) << 2;
    const int A1 = (sg | 4  | gate) << 2;
    const int A2 = (sg | 8  | gate) << 2;
    const int A3 = (sg | 12 | gate) << 2;

    float hw[HH];
    #pragma unroll
    for (int j = 0; j < HH; ++j) hw[j] = 0.f;
    float cs0 = 0.f, cs1 = 0.f;
    float h0 = 0.f, h1 = 0.f;

    const float* xp = inp + (size_t)b * DD;
    const int jj = 2 * part + (gate & 1);          // store slot (gates 2,3 duplicate 0,1)
    float* op = out + (size_t)b * HH + jj;

    // prefetch x_0
    float4 px0 = *(const float4*)(xp + 0);
    float4 px1 = *(const float4*)(xp + 4);
    float4 px2 = *(const float4*)(xp + 8);
    float4 px3 = *(const float4*)(xp + 12);

    #pragma unroll 1
    for (int t = 0; t < TT; ++t) {
        // ---- x-part of matvec directly from prefetch regs (no xv[] copies) ----
        float a0 = bs0, a1 = bs1;
        a0 = fmaf(w0[0],  px0.x, a0); a1 = fmaf(w1[0],  px0.x, a1);
        a0 = fmaf(w0[1],  px0.y, a0); a1 = fmaf(w1[1],  px0.y, a1);
        a0 = fmaf(w0[2],  px0.z, a0); a1 = fmaf(w1[2],  px0.z, a1);
        a0 = fmaf(w0[3],  px0.w, a0); a1 = fmaf(w1[3],  px0.w, a1);
        a0 = fmaf(w0[4],  px1.x, a0); a1 = fmaf(w1[4],  px1.x, a1);
        a0 = fmaf(w0[5],  px1.y, a0); a1 = fmaf(w1[5],  px1.y, a1);
        a0 = fmaf(w0[6],  px1.z, a0); a1 = fmaf(w1[6],  px1.z, a1);
        a0 = fmaf(w0[7],  px1.w, a0); a1 = fmaf(w1[7],  px1.w, a1);
        a0 = fmaf(w0[8],  px2.x, a0); a1 = fmaf(w1[8],  px2.x, a1);
        a0 = fmaf(w0[9],  px2.y, a0); a1 = fmaf(w1[9],  px2.y, a1);
        a0 = fmaf(w0[10], px2.z, a0); a1 = fmaf(w1[10], px2.z, a1);
        a0 = fmaf(w0[11], px2.w, a0); a1 = fmaf(w1[11], px2.w, a1);
        a0 = fmaf(w0[12], px3.x, a0); a1 = fmaf(w1[12], px3.x, a1);
        a0 = fmaf(w0[13], px3.y, a0); a1 = fmaf(w1[13], px3.y, a1);
        a0 = fmaf(w0[14], px3.z, a0); a1 = fmaf(w1[14], px3.z, a1);
        a0 = fmaf(w0[15], px3.w, a0); a1 = fmaf(w1[15], px3.w, a1);

        // ---- prefetch next x (px regs now free) ----
        const float* xn = xp + ((t < TT - 1) ? (size_t)BB * DD : 0);
        px0 = *(const float4*)(xn + 0);
        px1 = *(const float4*)(xn + 4);
        px2 = *(const float4*)(xn + 8);
        px3 = *(const float4*)(xn + 12);
        xp = xn;

        // ---- h-part of matvec ----
        #pragma unroll
        for (int j = 0; j < HH; ++j) { a0 = fmaf(w0[DD + j], hw[j], a0); a1 = fmaf(w1[DD + j], hw[j], a1); }

        // ---- own-wire trig + Bloch (2 wires; dedup: no replicated trig) ----
        float ar0 = a0 * INV_2PI, ar1 = a1 * INV_2PI;
        float sa0 = __builtin_amdgcn_sinf(ar0), ca0 = __builtin_amdgcn_cosf(ar0);
        float sa1 = __builtin_amdgcn_sinf(ar1), ca1 = __builtin_amdgcn_cosf(ar1);
        float bx0 = s1o0 * ca0, bz0 = c1o0 * ca0;   // sy0 = sa0
        float bx1 = s1o1 * ca1, bz1 = c1o1 * ca1;   // sy1 = sa1

        // ---- gather all 8 wires' Bloch comps via bpermute (no butterflies) ----
        float bxv[HH], syv[HH], bzv[HH];
        bxv[0] = bperm(A0, bx0); bxv[1] = bperm(A0, bx1);
        bxv[2] = bperm(A1, bx0); bxv[3] = bperm(A1, bx1);
        bxv[4] = bperm(A2, bx0); bxv[5] = bperm(A2, bx1);
        bxv[6] = bperm(A3, bx0); bxv[7] = bperm(A3, bx1);
        syv[0] = bperm(A0, sa0); syv[1] = bperm(A0, sa1);
        syv[2] = bperm(A1, sa0); syv[3] = bperm(A1, sa1);
        syv[4] = bperm(A2, sa0); syv[5] = bperm(A2, sa1);
        syv[6] = bperm(A3, sa0); syv[7] = bperm(A3, sa1);
        bzv[0] = bperm(A0, bz0); bzv[1] = bperm(A0, bz1);
        bzv[2] = bperm(A1, bz0); bzv[3] = bperm(A1, bz1);
        bzv[4] = bperm(A2, bz0); bzv[5] = bperm(A2, bz1);
        bzv[6] = bperm(A3, bz0); bzv[7] = bperm(A3, bz1);

        // ---- bond-2 transfer recursion -> E[8]  (verbatim-verified block) ----
        float E[HH];
        float f0 = g2[0] * bzv[0];
        float fx = hn[0] * bxv[0];
        float fy = hn[0] * syv[0];
        float fz = g2[0];
        E[0] = fmaf(bxv[1], fx, f0);
        #pragma unroll
        for (int w = 1; w < HH - 1; ++w) {
            float n0 = g2[w] * fmaf(bzv[w], fz, -(syv[w] * fy));
            float nx = hn[w] * fmaf(bxv[w], f0, fx);
            float ny = hn[w] * fmaf(syv[w], fz, bzv[w] * fy);
            float nz = g2[w] * fmaf(bxv[w], fx, f0);
            f0 = n0; fx = nx; fy = ny; fz = nz;
            E[w] = fmaf(bxv[w + 1], fx, f0);
        }
        {
            float n0 = g2[7] * fmaf(bzv[7], fz, -(syv[7] * fy));
            float nx = hn[7] * fmaf(bxv[7], f0, fx);
            E[7] = n0 + nx;
        }

        // ---- own 2 E values (select tree) ----
        float u0 = hi ? E[4] : E[0], u1 = hi ? E[5] : E[1];
        float u2 = hi ? E[6] : E[2], u3 = hi ? E[7] : E[3];
        float e0 = pl ? u2 : u0;
        float e1 = pl ? u3 : u1;

        // ---- gate nonlinearity (own 2 j's) ----
        float G0 = fmaf(kPost, fast_rcp(1.0f + __expf(kPre * e0)), kAdd);
        float G1 = fmaf(kPost, fast_rcp(1.0f + __expf(kPre * e1)), kAdd);

        // ---- quad (gate) exchange + LSTM pointwise ----
        {
            float fj = QBCAST(G0, 0), ij = QBCAST(G0, 1), uj = QBCAST(G0, 2), oj = QBCAST(G0, 3);
            cs0 = fmaf(fj, cs0, ij * uj);
            float th = fmaf(2.0f, fast_rcp(1.0f + __expf(-2.0f * cs0)), -1.0f);
            h0 = oj * th;
        }
        {
            float fj = QBCAST(G1, 0), ij = QBCAST(G1, 1), uj = QBCAST(G1, 2), oj = QBCAST(G1, 3);
            cs1 = fmaf(fj, cs1, ij * uj);
            float th = fmaf(2.0f, fast_rcp(1.0f + __expf(-2.0f * cs1)), -1.0f);
            h1 = oj * th;
        }

        // ---- gather h back to full hw[8] via bpermute ----
        hw[0] = bperm(A0, h0); hw[1] = bperm(A0, h1);
        hw[2] = bperm(A1, h0); hw[3] = bperm(A1, h1);
        hw[4] = bperm(A2, h0); hw[5] = bperm(A2, h1);
        hw[6] = bperm(A3, h0); hw[7] = bperm(A3, h1);

        // ---- store h_t (all lanes; gates 2,3 duplicate 0,1 with identical values) ----
        *op = (gate & 1) ? h1 : h0;
        op += (size_t)BB * HH;
    }

    // ---- final hx, cx (all lanes; duplicates benign) ----
    const size_t hx_off = (size_t)TT * BB * HH;
    out[hx_off + (size_t)b * HH + jj] = (gate & 1) ? h1 : h0;
    out[hx_off + (size_t)BB * HH + (size_t)b * HH + jj] = (gate & 1) ? cs1 : cs0;
}

extern "C" void kernel_launch(void* const* d_in, const int* in_sizes, int n_in,
                              void* d_out, int out_size, void* d_ws, size_t ws_size,
                              hipStream_t stream) {
    (void)in_sizes; (void)n_in; (void)d_ws; (void)ws_size; (void)out_size;
    const float* inp = (const float*)d_in[0];
    const float* Wf  = (const float*)d_in[1];
    const float* bf  = (const float*)d_in[2];
    const float* Wi  = (const float*)d_in[3];
    const float* bi  = (const float*)d_in[4];
    const float* Wu  = (const float*)d_in[5];
    const float* bu  = (const float*)d_in[6];
    const float* Wo  = (const float*)d_in[7];
    const float* bo  = (const float*)d_in[8];
    const float* pf  = (const float*)d_in[9];
    const float* pi  = (const float*)d_in[10];
    const float* pu  = (const float*)d_in[11];
    const float* po  = (const float*)d_in[12];
    float* out = (float*)d_out;

    const int threads = BB * 16;   // 16 lanes (4 gates x 4 parts) per sample
    dim3 block(256);
    dim3 grid(threads / 256);
    qlstm_fused_kernel<<<grid, block, 0, stream>>>(inp, Wf, bf, Wi, bi, Wu, bu,
                                                   Wo, bo, pf, pi, pu, po, out);
}

// Round 8
// 238.826 us; speedup vs baseline: 1.1805x; 1.1805x over previous
//
#include <hip/hip_runtime.h>

#define TT 256
#define BB 8192
#define DD 16
#define HH 8

#define INV_2PI 0.15915494309189535f

__device__ __forceinline__ float fast_rcp(float v) { return __builtin_amdgcn_rcpf(v); }

// pull from lane^4 (partner part, bit0) : BitMode offset = (xor<<10)|(or<<5)|and
__device__ __forceinline__ float swz_xor4(float v) {
    return __int_as_float(__builtin_amdgcn_ds_swizzle(__float_as_int(v), 0x101F));
}
// pull from lane^8 (partner part, bit1)
__device__ __forceinline__ float swz_xor8(float v) {
    return __int_as_float(__builtin_amdgcn_ds_swizzle(__float_as_int(v), 0x201F));
}
// quad broadcast via DPP: every lane of the quad reads lane (quadbase + g)
#define QBCAST(x, g) __int_as_float(__builtin_amdgcn_mov_dpp(__float_as_int(x), (g)*0x55, 0xF, 0xF, true))

__global__ __launch_bounds__(256, 2)
void qlstm_fused_kernel(const float* __restrict__ inp,
                        const float* __restrict__ Wf, const float* __restrict__ bfv,
                        const float* __restrict__ Wi, const float* __restrict__ biv,
                        const float* __restrict__ Wu, const float* __restrict__ buv,
                        const float* __restrict__ Wo, const float* __restrict__ bov,
                        const float* __restrict__ pf, const float* __restrict__ pi,
                        const float* __restrict__ pu, const float* __restrict__ po,
                        float* __restrict__ out)
{
    const int tid  = blockIdx.x * blockDim.x + threadIdx.x;
    const int gate = tid & 3;          // 0=f, 1=i, 2=u(g), 3=o  (quad lanes)
    const int part = (tid >> 2) & 3;   // owns matvec rows / wires 2*part, 2*part+1
    const int b    = tid >> 4;         // sample

    const float* Wg = (gate == 0) ? Wf  : (gate == 1) ? Wi  : (gate == 2) ? Wu  : Wo;
    const float* bg = (gate == 0) ? bfv : (gate == 1) ? biv : (gate == 2) ? buv : bov;
    const float* pp = (gate == 0) ? pf  : (gate == 1) ? pi  : (gate == 2) ? pu  : po;

    // ---- own 2 weight rows (48 floats) + biases, PRE-SCALED by 1/2pi so the
    //      matvec result is directly in revolutions for v_sin/v_cos ----
    const int r0 = 2 * part;
    float w0[24], w1[24];
    {
        const float* p0 = Wg + r0 * 24;
        const float* p1 = Wg + (r0 + 1) * 24;
        #pragma unroll
        for (int k = 0; k < 6; ++k) {
            float4 v0 = *(const float4*)(p0 + 4 * k);
            float4 v1 = *(const float4*)(p1 + 4 * k);
            w0[4*k+0] = v0.x * INV_2PI; w0[4*k+1] = v0.y * INV_2PI;
            w0[4*k+2] = v0.z * INV_2PI; w0[4*k+3] = v0.w * INV_2PI;
            w1[4*k+0] = v1.x * INV_2PI; w1[4*k+1] = v1.y * INV_2PI;
            w1[4*k+2] = v1.z * INV_2PI; w1[4*k+3] = v1.w * INV_2PI;
        }
    }
    const float bs0 = bg[r0] * INV_2PI, bs1 = bg[r0 + 1] * INV_2PI;

    // ---- layer-1 trig for OWN 2 wires only; layer-2 coeffs for all 8 ----
    float s1o0, c1o0, s1o1, c1o1;
    __sincosf(pp[r0],     &s1o0, &c1o0);
    __sincosf(pp[r0 + 1], &s1o1, &c1o1);
    float g2[HH], hn[HH];
    #pragma unroll
    for (int w = 0; w < HH; ++w) {
        float s, c;
        __sincosf(pp[HH + w], &s, &c);
        g2[w] = c; hn[w] = -s;
    }

    // gate nonlinearity constants: sigmoid for f/i/o; tanh(v) = 2*sig(2v)-1 for u
    const float kPre  = (gate == 2) ? -2.0f : -1.0f;
    const float kPost = (gate == 2) ?  2.0f :  1.0f;
    const float kAdd  = (gate == 2) ? -1.0f :  0.0f;

    const bool pl = (part & 1) != 0;   // position within xor4 pair
    const bool hi = (part & 2) != 0;   // which 4-wire group we own

    // 2-stage all-gather butterfly (verified in R4/R6), applied to a value-pair
    auto bfly = [&](float v0, float v1, float* o) {
        float o0 = swz_xor4(v0), o1 = swz_xor4(v1);
        float q0 = pl ? o0 : v0, q1 = pl ? o1 : v1;
        float q2 = pl ? v0 : o0, q3 = pl ? v1 : o1;
        float r0_ = swz_xor8(q0), r1_ = swz_xor8(q1);
        float r2_ = swz_xor8(q2), r3_ = swz_xor8(q3);
        o[0] = hi ? r0_ : q0;  o[1] = hi ? r1_ : q1;
        o[2] = hi ? r2_ : q2;  o[3] = hi ? r3_ : q3;
        o[4] = hi ? q0 : r0_;  o[5] = hi ? q1 : r1_;
        o[6] = hi ? q2 : r2_;  o[7] = hi ? q3 : r3_;
    };

    float hw[HH];
    #pragma unroll
    for (int j = 0; j < HH; ++j) hw[j] = 0.f;
    float cs0 = 0.f, cs1 = 0.f, h0 = 0.f, h1 = 0.f;

    const float* xp = inp + (size_t)b * DD;
    const int jj = 2 * part + (gate & 1);          // store slot (gates 2,3 duplicate 0,1)
    float* op = out + (size_t)b * HH + jj;

    // prefetch x_0
    float4 px0 = *(const float4*)(xp + 0);
    float4 px1 = *(const float4*)(xp + 4);
    float4 px2 = *(const float4*)(xp + 8);
    float4 px3 = *(const float4*)(xp + 12);

    #pragma unroll 2
    for (int t = 0; t < TT; ++t) {
        // ---- tree-ified matvec: three short independent chains per row ----
        float a0A = fmaf(w0[0],  px0.x, bs0);
        a0A = fmaf(w0[1],  px0.y, a0A);  a0A = fmaf(w0[2],  px0.z, a0A);
        a0A = fmaf(w0[3],  px0.w, a0A);  a0A = fmaf(w0[4],  px1.x, a0A);
        a0A = fmaf(w0[5],  px1.y, a0A);  a0A = fmaf(w0[6],  px1.z, a0A);
        a0A = fmaf(w0[7],  px1.w, a0A);
        float a0B = w0[8] * px2.x;
        a0B = fmaf(w0[9],  px2.y, a0B);  a0B = fmaf(w0[10], px2.z, a0B);
        a0B = fmaf(w0[11], px2.w, a0B);  a0B = fmaf(w0[12], px3.x, a0B);
        a0B = fmaf(w0[13], px3.y, a0B);  a0B = fmaf(w0[14], px3.z, a0B);
        a0B = fmaf(w0[15], px3.w, a0B);
        float a1A = fmaf(w1[0],  px0.x, bs1);
        a1A = fmaf(w1[1],  px0.y, a1A);  a1A = fmaf(w1[2],  px0.z, a1A);
        a1A = fmaf(w1[3],  px0.w, a1A);  a1A = fmaf(w1[4],  px1.x, a1A);
        a1A = fmaf(w1[5],  px1.y, a1A);  a1A = fmaf(w1[6],  px1.z, a1A);
        a1A = fmaf(w1[7],  px1.w, a1A);
        float a1B = w1[8] * px2.x;
        a1B = fmaf(w1[9],  px2.y, a1B);  a1B = fmaf(w1[10], px2.z, a1B);
        a1B = fmaf(w1[11], px2.w, a1B);  a1B = fmaf(w1[12], px3.x, a1B);
        a1B = fmaf(w1[13], px3.y, a1B);  a1B = fmaf(w1[14], px3.z, a1B);
        a1B = fmaf(w1[15], px3.w, a1B);

        // ---- prefetch next x (px regs now free) ----
        const float* xn = xp + ((t < TT - 1) ? (size_t)BB * DD : 0);
        px0 = *(const float4*)(xn + 0);
        px1 = *(const float4*)(xn + 4);
        px2 = *(const float4*)(xn + 8);
        px3 = *(const float4*)(xn + 12);
        xp = xn;

        // ---- h-part: short 8-chain (h is the late arrival) ----
        float a0C = w0[16] * hw[0];
        a0C = fmaf(w0[17], hw[1], a0C);  a0C = fmaf(w0[18], hw[2], a0C);
        a0C = fmaf(w0[19], hw[3], a0C);  a0C = fmaf(w0[20], hw[4], a0C);
        a0C = fmaf(w0[21], hw[5], a0C);  a0C = fmaf(w0[22], hw[6], a0C);
        a0C = fmaf(w0[23], hw[7], a0C);
        float a1C = w1[16] * hw[0];
        a1C = fmaf(w1[17], hw[1], a1C);  a1C = fmaf(w1[18], hw[2], a1C);
        a1C = fmaf(w1[19], hw[3], a1C);  a1C = fmaf(w1[20], hw[4], a1C);
        a1C = fmaf(w1[21], hw[5], a1C);  a1C = fmaf(w1[22], hw[6], a1C);
        a1C = fmaf(w1[23], hw[7], a1C);
        float a0 = (a0A + a0B) + a0C;    // in revolutions
        float a1 = (a1A + a1B) + a1C;

        // ---- trig for OWN 2 wires only (dedup: 4 trans, not 16) ----
        float sa0 = __builtin_amdgcn_sinf(a0), ca0 = __builtin_amdgcn_cosf(a0);
        float sa1 = __builtin_amdgcn_sinf(a1), ca1 = __builtin_amdgcn_cosf(a1);
        float bx0 = s1o0 * ca0, bz0 = c1o0 * ca0;   // own Bloch comps (sy = sa)
        float bx1 = s1o1 * ca1, bz1 = c1o1 * ca1;

        // ---- butterfly the 3 Bloch components to all lanes ----
        float bxv[HH], syv[HH], bzv[HH];
        bfly(bx0, bx1, bxv);
        bfly(sa0, sa1, syv);
        bfly(bz0, bz1, bzv);

        // ---- bond-2 transfer recursion -> E[8]  (verbatim-verified block) ----
        float E[HH];
        float f0 = g2[0] * bzv[0];
        float fx = hn[0] * bxv[0];
        float fy = hn[0] * syv[0];
        float fz = g2[0];
        E[0] = fmaf(bxv[1], fx, f0);
        #pragma unroll
        for (int w = 1; w < HH - 1; ++w) {
            float n0 = g2[w] * fmaf(bzv[w], fz, -(syv[w] * fy));
            float nx = hn[w] * fmaf(bxv[w], f0, fx);
            float ny = hn[w] * fmaf(syv[w], fz, bzv[w] * fy);
            float nz = g2[w] * fmaf(bxv[w], fx, f0);
            f0 = n0; fx = nx; fy = ny; fz = nz;
            E[w] = fmaf(bxv[w + 1], fx, f0);
        }
        {
            float n0 = g2[7] * fmaf(bzv[7], fz, -(syv[7] * fy));
            float nx = hn[7] * fmaf(bxv[7], f0, fx);
            E[7] = n0 + nx;
        }

        // ---- own 2 E values (select tree) ----
        float u0 = hi ? E[4] : E[0], u1 = hi ? E[5] : E[1];
        float u2 = hi ? E[6] : E[2], u3 = hi ? E[7] : E[3];
        float e0 = pl ? u2 : u0;
        float e1 = pl ? u3 : u1;

        // ---- gate nonlinearity (own 2 j's) ----
        float G0 = fmaf(kPost, fast_rcp(1.0f + __expf(kPre * e0)), kAdd);
        float G1 = fmaf(kPost, fast_rcp(1.0f + __expf(kPre * e1)), kAdd);

        // ---- quad (gate) exchange + LSTM pointwise ----
        {
            float fj = QBCAST(G0, 0), ij = QBCAST(G0, 1), uj = QBCAST(G0, 2), oj = QBCAST(G0, 3);
            cs0 = fmaf(fj, cs0, ij * uj);
            float th = fmaf(2.0f, fast_rcp(1.0f + __expf(-2.0f * cs0)), -1.0f);
            h0 = oj * th;
        }
        {
            float fj = QBCAST(G1, 0), ij = QBCAST(G1, 1), uj = QBCAST(G1, 2), oj = QBCAST(G1, 3);
            cs1 = fmaf(fj, cs1, ij * uj);
            float th = fmaf(2.0f, fast_rcp(1.0f + __expf(-2.0f * cs1)), -1.0f);
            h1 = oj * th;
        }

        // ---- butterfly h back to full hw[8] ----
        bfly(h0, h1, hw);

        // ---- store h_t (all lanes; gates 2,3 duplicate 0,1 with identical values) ----
        *op = (gate & 1) ? h1 : h0;
        op += (size_t)BB * HH;
    }

    // ---- final hx, cx (all lanes; duplicates benign) ----
    const size_t hx_off = (size_t)TT * BB * HH;
    out[hx_off + (size_t)b * HH + jj] = (gate & 1) ? h1 : h0;
    out[hx_off + (size_t)BB * HH + (size_t)b * HH + jj] = (gate & 1) ? cs1 : cs0;
}

extern "C" void kernel_launch(void* const* d_in, const int* in_sizes, int n_in,
                              void* d_out, int out_size, void* d_ws, size_t ws_size,
                              hipStream_t stream) {
    (void)in_sizes; (void)n_in; (void)d_ws; (void)ws_size; (void)out_size;
    const float* inp = (const float*)d_in[0];
    const float* Wf  = (const float*)d_in[1];
    const float* bf  = (const float*)d_in[2];
    const float* Wi  = (const float*)d_in[3];
    const float* bi  = (const float*)d_in[4];
    const float* Wu  = (const float*)d_in[5];
    const float* bu  = (const float*)d_in[6];
    const float* Wo  = (const float*)d_in[7];
    const float* bo  = (const float*)d_in[8];
    const float* pf  = (const float*)d_in[9];
    const float* pi  = (const float*)d_in[10];
    const float* pu  = (const float*)d_in[11];
    const float* po  = (const float*)d_in[12];
    float* out = (float*)d_out;

    const int threads = BB * 16;   // 16 lanes (4 gates x 4 parts) per sample
    dim3 block(256);
    dim3 grid(threads / 256);
    qlstm_fused_kernel<<<grid, block, 0, stream>>>(inp, Wf, bf, Wi, bi, Wu, bu,
                                                   Wo, bo, pf, pi, pu, po, out);
}

// Round 9
// 203.070 us; speedup vs baseline: 1.3884x; 1.1761x over previous
//
#include <hip/hip_runtime.h>

#define TT 256
#define BB 8192
#define DD 16
#define HH 8

#define INV_2PI 0.15915494309189535f

__device__ __forceinline__ float fast_rcp(float v) { return __builtin_amdgcn_rcpf(v); }

// Direct gather of "part j's value" within the 16-lane sample group:
// BitMode new_lane = ((lane & 0b10011) | (j<<2)) — keeps gate bits + sample bit4.
#define SWZP0(v) __int_as_float(__builtin_amdgcn_ds_swizzle(__float_as_int(v), 0x013))
#define SWZP1(v) __int_as_float(__builtin_amdgcn_ds_swizzle(__float_as_int(v), 0x093))
#define SWZP2(v) __int_as_float(__builtin_amdgcn_ds_swizzle(__float_as_int(v), 0x113))
#define SWZP3(v) __int_as_float(__builtin_amdgcn_ds_swizzle(__float_as_int(v), 0x193))

// quad broadcast via DPP: every lane of the quad reads lane (quadbase + g)
#define QBCAST(x, g) __int_as_float(__builtin_amdgcn_mov_dpp(__float_as_int(x), (g)*0x55, 0xF, 0xF, true))

__global__ __launch_bounds__(256, 2)
void qlstm_fused_kernel(const float* __restrict__ inp,
                        const float* __restrict__ Wf, const float* __restrict__ bfv,
                        const float* __restrict__ Wi, const float* __restrict__ biv,
                        const float* __restrict__ Wu, const float* __restrict__ buv,
                        const float* __restrict__ Wo, const float* __restrict__ bov,
                        const float* __restrict__ pf, const float* __restrict__ pi,
                        const float* __restrict__ pu, const float* __restrict__ po,
                        float* __restrict__ out)
{
    const int tid  = blockIdx.x * blockDim.x + threadIdx.x;
    const int gate = tid & 3;          // 0=f, 1=i, 2=u(g), 3=o  (quad lanes)
    const int part = (tid >> 2) & 3;   // owns matvec rows / wires 2*part, 2*part+1
    const int b    = tid >> 4;         // sample

    const float* Wg = (gate == 0) ? Wf  : (gate == 1) ? Wi  : (gate == 2) ? Wu  : Wo;
    const float* bg = (gate == 0) ? bfv : (gate == 1) ? biv : (gate == 2) ? buv : bov;
    const float* pp = (gate == 0) ? pf  : (gate == 1) ? pi  : (gate == 2) ? pu  : po;

    // ---- own 2 weight rows (48 floats) + biases, PRE-SCALED by 1/2pi so the
    //      matvec result is directly in revolutions for v_sin/v_cos ----
    const int r0 = 2 * part;
    float w0[24], w1[24];
    {
        const float* p0 = Wg + r0 * 24;
        const float* p1 = Wg + (r0 + 1) * 24;
        #pragma unroll
        for (int k = 0; k < 6; ++k) {
            float4 v0 = *(const float4*)(p0 + 4 * k);
            float4 v1 = *(const float4*)(p1 + 4 * k);
            w0[4*k+0] = v0.x * INV_2PI; w0[4*k+1] = v0.y * INV_2PI;
            w0[4*k+2] = v0.z * INV_2PI; w0[4*k+3] = v0.w * INV_2PI;
            w1[4*k+0] = v1.x * INV_2PI; w1[4*k+1] = v1.y * INV_2PI;
            w1[4*k+2] = v1.z * INV_2PI; w1[4*k+3] = v1.w * INV_2PI;
        }
    }
    const float bs0 = bg[r0] * INV_2PI, bs1 = bg[r0 + 1] * INV_2PI;

    // ---- layer-1 trig for OWN 2 wires only; layer-2 coeffs for all 8 ----
    float s1o0, c1o0, s1o1, c1o1;
    __sincosf(pp[r0],     &s1o0, &c1o0);
    __sincosf(pp[r0 + 1], &s1o1, &c1o1);
    float g2[HH], hn[HH];
    #pragma unroll
    for (int w = 0; w < HH; ++w) {
        float s, c;
        __sincosf(pp[HH + w], &s, &c);
        g2[w] = c; hn[w] = -s;
    }

    // gate nonlinearity constants: sigmoid for f/i/o; tanh(v) = 2*sig(2v)-1 for u
    const float kPre  = (gate == 2) ? -2.0f : -1.0f;
    const float kPost = (gate == 2) ?  2.0f :  1.0f;
    const float kAdd  = (gate == 2) ? -1.0f :  0.0f;

    const bool pl = (part & 1) != 0;   // for own-E select tree
    const bool hi = (part & 2) != 0;

    float hw[HH];
    #pragma unroll
    for (int j = 0; j < HH; ++j) hw[j] = 0.f;
    float cs0 = 0.f, cs1 = 0.f, h0 = 0.f, h1 = 0.f;

    const float* xp = inp + (size_t)b * DD;
    const int jj = 2 * part + (gate & 1);          // store slot (gates 2,3 duplicate 0,1)
    float* op = out + (size_t)b * HH + jj;

    // prefetch x_0
    float4 px0 = *(const float4*)(xp + 0);
    float4 px1 = *(const float4*)(xp + 4);
    float4 px2 = *(const float4*)(xp + 8);
    float4 px3 = *(const float4*)(xp + 12);

    #pragma unroll 2
    for (int t = 0; t < TT; ++t) {
        // ---- tree-ified matvec: three short independent chains per row ----
        float a0A = fmaf(w0[0],  px0.x, bs0);
        a0A = fmaf(w0[1],  px0.y, a0A);  a0A = fmaf(w0[2],  px0.z, a0A);
        a0A = fmaf(w0[3],  px0.w, a0A);  a0A = fmaf(w0[4],  px1.x, a0A);
        a0A = fmaf(w0[5],  px1.y, a0A);  a0A = fmaf(w0[6],  px1.z, a0A);
        a0A = fmaf(w0[7],  px1.w, a0A);
        float a0B = w0[8] * px2.x;
        a0B = fmaf(w0[9],  px2.y, a0B);  a0B = fmaf(w0[10], px2.z, a0B);
        a0B = fmaf(w0[11], px2.w, a0B);  a0B = fmaf(w0[12], px3.x, a0B);
        a0B = fmaf(w0[13], px3.y, a0B);  a0B = fmaf(w0[14], px3.z, a0B);
        a0B = fmaf(w0[15], px3.w, a0B);
        float a1A = fmaf(w1[0],  px0.x, bs1);
        a1A = fmaf(w1[1],  px0.y, a1A);  a1A = fmaf(w1[2],  px0.z, a1A);
        a1A = fmaf(w1[3],  px0.w, a1A);  a1A = fmaf(w1[4],  px1.x, a1A);
        a1A = fmaf(w1[5],  px1.y, a1A);  a1A = fmaf(w1[6],  px1.z, a1A);
        a1A = fmaf(w1[7],  px1.w, a1A);
        float a1B = w1[8] * px2.x;
        a1B = fmaf(w1[9],  px2.y, a1B);  a1B = fmaf(w1[10], px2.z, a1B);
        a1B = fmaf(w1[11], px2.w, a1B);  a1B = fmaf(w1[12], px3.x, a1B);
        a1B = fmaf(w1[13], px3.y, a1B);  a1B = fmaf(w1[14], px3.z, a1B);
        a1B = fmaf(w1[15], px3.w, a1B);

        // ---- prefetch next x (px regs now free) ----
        const float* xn = xp + ((t < TT - 1) ? (size_t)BB * DD : 0);
        px0 = *(const float4*)(xn + 0);
        px1 = *(const float4*)(xn + 4);
        px2 = *(const float4*)(xn + 8);
        px3 = *(const float4*)(xn + 12);
        xp = xn;

        // ---- h-part: short 8-chain (h is the late arrival) ----
        float a0C = w0[16] * hw[0];
        a0C = fmaf(w0[17], hw[1], a0C);  a0C = fmaf(w0[18], hw[2], a0C);
        a0C = fmaf(w0[19], hw[3], a0C);  a0C = fmaf(w0[20], hw[4], a0C);
        a0C = fmaf(w0[21], hw[5], a0C);  a0C = fmaf(w0[22], hw[6], a0C);
        a0C = fmaf(w0[23], hw[7], a0C);
        float a1C = w1[16] * hw[0];
        a1C = fmaf(w1[17], hw[1], a1C);  a1C = fmaf(w1[18], hw[2], a1C);
        a1C = fmaf(w1[19], hw[3], a1C);  a1C = fmaf(w1[20], hw[4], a1C);
        a1C = fmaf(w1[21], hw[5], a1C);  a1C = fmaf(w1[22], hw[6], a1C);
        a1C = fmaf(w1[23], hw[7], a1C);
        float a0 = (a0A + a0B) + a0C;    // in revolutions
        float a1 = (a1A + a1B) + a1C;

        // ---- trig for OWN 2 wires only (4 trans, not 16) ----
        float sa0 = __builtin_amdgcn_sinf(a0), ca0 = __builtin_amdgcn_cosf(a0);
        float sa1 = __builtin_amdgcn_sinf(a1), ca1 = __builtin_amdgcn_cosf(a1);
        float bx0 = s1o0 * ca0, bz0 = c1o0 * ca0;   // own Bloch comps (sy = sa)
        float bx1 = s1o1 * ca1, bz1 = c1o1 * ca1;

        // ---- single-stage direct gathers: wire 2j / 2j+1 from part j ----
        float bxv[HH], syv[HH], bzv[HH];
        bxv[0] = SWZP0(bx0); bxv[1] = SWZP0(bx1);
        bxv[2] = SWZP1(bx0); bxv[3] = SWZP1(bx1);
        bxv[4] = SWZP2(bx0); bxv[5] = SWZP2(bx1);
        bxv[6] = SWZP3(bx0); bxv[7] = SWZP3(bx1);
        syv[0] = SWZP0(sa0); syv[1] = SWZP0(sa1);
        syv[2] = SWZP1(sa0); syv[3] = SWZP1(sa1);
        syv[4] = SWZP2(sa0); syv[5] = SWZP2(sa1);
        syv[6] = SWZP3(sa0); syv[7] = SWZP3(sa1);
        bzv[0] = SWZP0(bz0); bzv[1] = SWZP0(bz1);
        bzv[2] = SWZP1(bz0); bzv[3] = SWZP1(bz1);
        bzv[4] = SWZP2(bz0); bzv[5] = SWZP2(bz1);
        bzv[6] = SWZP3(bz0); bzv[7] = SWZP3(bz1);

        // ---- bond-2 transfer recursion -> E[8]  (verbatim-verified block) ----
        float E[HH];
        float f0 = g2[0] * bzv[0];
        float fx = hn[0] * bxv[0];
        float fy = hn[0] * syv[0];
        float fz = g2[0];
        E[0] = fmaf(bxv[1], fx, f0);
        #pragma unroll
        for (int w = 1; w < HH - 1; ++w) {
            float n0 = g2[w] * fmaf(bzv[w], fz, -(syv[w] * fy));
            float nx = hn[w] * fmaf(bxv[w], f0, fx);
            float ny = hn[w] * fmaf(syv[w], fz, bzv[w] * fy);
            float nz = g2[w] * fmaf(bxv[w], fx, f0);
            f0 = n0; fx = nx; fy = ny; fz = nz;
            E[w] = fmaf(bxv[w + 1], fx, f0);
        }
        {
            float n0 = g2[7] * fmaf(bzv[7], fz, -(syv[7] * fy));
            float nx = hn[7] * fmaf(bxv[7], f0, fx);
            E[7] = n0 + nx;
        }

        // ---- own 2 E values (select tree) ----
        float u0 = hi ? E[4] : E[0], u1 = hi ? E[5] : E[1];
        float u2 = hi ? E[6] : E[2], u3 = hi ? E[7] : E[3];
        float e0 = pl ? u2 : u0;
        float e1 = pl ? u3 : u1;

        // ---- gate nonlinearity (own 2 j's) ----
        float G0 = fmaf(kPost, fast_rcp(1.0f + __expf(kPre * e0)), kAdd);
        float G1 = fmaf(kPost, fast_rcp(1.0f + __expf(kPre * e1)), kAdd);

        // ---- quad (gate) exchange + LSTM pointwise ----
        {
            float fj = QBCAST(G0, 0), ij = QBCAST(G0, 1), uj = QBCAST(G0, 2), oj = QBCAST(G0, 3);
            cs0 = fmaf(fj, cs0, ij * uj);
            float th = fmaf(2.0f, fast_rcp(1.0f + __expf(-2.0f * cs0)), -1.0f);
            h0 = oj * th;
        }
        {
            float fj = QBCAST(G1, 0), ij = QBCAST(G1, 1), uj = QBCAST(G1, 2), oj = QBCAST(G1, 3);
            cs1 = fmaf(fj, cs1, ij * uj);
            float th = fmaf(2.0f, fast_rcp(1.0f + __expf(-2.0f * cs1)), -1.0f);
            h1 = oj * th;
        }

        // ---- single-stage gather of h back to full hw[8] ----
        hw[0] = SWZP0(h0); hw[1] = SWZP0(h1);
        hw[2] = SWZP1(h0); hw[3] = SWZP1(h1);
        hw[4] = SWZP2(h0); hw[5] = SWZP2(h1);
        hw[6] = SWZP3(h0); hw[7] = SWZP3(h1);

        // ---- store h_t (all lanes; gates 2,3 duplicate 0,1 with identical values) ----
        *op = (gate & 1) ? h1 : h0;
        op += (size_t)BB * HH;
    }

    // ---- final hx, cx (all lanes; duplicates benign) ----
    const size_t hx_off = (size_t)TT * BB * HH;
    out[hx_off + (size_t)b * HH + jj] = (gate & 1) ? h1 : h0;
    out[hx_off + (size_t)BB * HH + (size_t)b * HH + jj] = (gate & 1) ? cs1 : cs0;
}

extern "C" void kernel_launch(void* const* d_in, const int* in_sizes, int n_in,
                              void* d_out, int out_size, void* d_ws, size_t ws_size,
                              hipStream_t stream) {
    (void)in_sizes; (void)n_in; (void)d_ws; (void)ws_size; (void)out_size;
    const float* inp = (const float*)d_in[0];
    const float* Wf  = (const float*)d_in[1];
    const float* bf  = (const float*)d_in[2];
    const float* Wi  = (const float*)d_in[3];
    const float* bi  = (const float*)d_in[4];
    const float* Wu  = (const float*)d_in[5];
    const float* bu  = (const float*)d_in[6];
    const float* Wo  = (const float*)d_in[7];
    const float* bo  = (const float*)d_in[8];
    const float* pf  = (const float*)d_in[9];
    const float* pi  = (const float*)d_in[10];
    const float* pu  = (const float*)d_in[11];
    const float* po  = (const float*)d_in[12];
    float* out = (float*)d_out;

    const int threads = BB * 16;   // 16 lanes (4 gates x 4 parts) per sample
    dim3 block(256);
    dim3 grid(threads / 256);
    qlstm_fused_kernel<<<grid, block, 0, stream>>>(inp, Wf, bf, Wi, bi, Wu, bu,
                                                   Wo, bo, pf, pi, pu, po, out);
}